// Round 1
// baseline (228.464 us; speedup 1.0000x reference)
//
#include <hip/hip_runtime.h>
#include <hip/hip_bf16.h>

#define IN_DIM 2048
#define OUT_DIM 2048
#define NE 8
#define NR 8
#define M_TOT 8192          // B*S = 4*2048
#define RANK_PAD 96         // 8 shared + 64 expert + 24 zero pad
#define K_EXT 2144          // IN_DIM + RANK_PAD

typedef short short8 __attribute__((ext_vector_type(8)));
typedef unsigned short ushort8 __attribute__((ext_vector_type(8)));
typedef float floatx4 __attribute__((ext_vector_type(4)));

__device__ __forceinline__ unsigned short f2bf(float f) {
    union { float f; unsigned u; } v; v.f = f;
    unsigned r = v.u + 0x7FFFu + ((v.u >> 16) & 1u);   // round-to-nearest-even
    return (unsigned short)(r >> 16);
}

__device__ __forceinline__ void gld_lds16(const void* g, void* l) {
    __builtin_amdgcn_global_load_lds(
        (const __attribute__((address_space(1))) void*)g,
        (__attribute__((address_space(3))) void*)l, 16, 0, 0);
}

// ---------------- prep: x -> bf16 into A_ext[:, 0:2048] ----------------
__global__ void prep_x(const float* __restrict__ x, unsigned short* __restrict__ Aext) {
    int m = blockIdx.x;          // one row per block
    int t = threadIdx.x;         // 256 threads * 8 elems = 2048
    const float4* src = (const float4*)(x + (size_t)m * IN_DIM + t * 8);
    float4 v0 = src[0], v1 = src[1];
    ushort8 o;
    o[0] = f2bf(v0.x); o[1] = f2bf(v0.y); o[2] = f2bf(v0.z); o[3] = f2bf(v0.w);
    o[4] = f2bf(v1.x); o[5] = f2bf(v1.y); o[6] = f2bf(v1.z); o[7] = f2bf(v1.w);
    *(ushort8*)(Aext + (size_t)m * K_EXT + t * 8) = o;
}

// ------------- prep: W -> bf16 into B_ext[:,0:2048]; B_cat into cols 2048+ -------------
__global__ void prep_w(const float* __restrict__ W, const float* __restrict__ Bs,
                       const float* __restrict__ Be, unsigned short* __restrict__ Bext) {
    int n = blockIdx.x;
    int t = threadIdx.x;
    const float4* src = (const float4*)(W + (size_t)n * IN_DIM + t * 8);
    float4 v0 = src[0], v1 = src[1];
    ushort8 o;
    o[0] = f2bf(v0.x); o[1] = f2bf(v0.y); o[2] = f2bf(v0.z); o[3] = f2bf(v0.w);
    o[4] = f2bf(v1.x); o[5] = f2bf(v1.y); o[6] = f2bf(v1.z); o[7] = f2bf(v1.w);
    *(ushort8*)(Bext + (size_t)n * K_EXT + t * 8) = o;
    if (t < RANK_PAD) {
        float v = 0.f;
        if (t < 8)       v = Bs[(size_t)t * OUT_DIM + n];          // B_s[r][n]
        else if (t < 72) v = Be[(size_t)(t - 8) * OUT_DIM + n];    // B_e[e][r][n], e*8+r = t-8
        Bext[(size_t)n * K_EXT + IN_DIM + t] = f2bf(v);
    }
}

// ------------- prep: A_catT[96][2048] bf16: row k' = column k' of [A_s | A_e...] -------------
__global__ void prep_acat(const float* __restrict__ As, const float* __restrict__ Ae,
                          unsigned short* __restrict__ AcatT) {
    int kp = blockIdx.x;          // 0..95
    int i0 = threadIdx.x * 8;
    ushort8 o;
#pragma unroll
    for (int j = 0; j < 8; ++j) {
        int i = i0 + j;
        float v = 0.f;
        if (kp < 8)       v = As[(size_t)i * NR + kp];
        else if (kp < 72) v = Ae[(size_t)((kp - 8) >> 3) * IN_DIM * NR + (size_t)i * NR + ((kp - 8) & 7)];
        o[j] = f2bf(v);
    }
    *(ushort8*)(AcatT + (size_t)kp * IN_DIM + i0) = o;
}

// ------------- T = x_bf16 @ A_cat (M=8192, N=96, K=2048), scaled by routing, -> A_ext cols 2048+ -------------
__global__ void tgemm(const unsigned short* __restrict__ Aext_ro,
                      unsigned short* __restrict__ Aext_w,
                      const unsigned short* __restrict__ AcatT,
                      const float* __restrict__ routing) {
    int lane = threadIdx.x;            // 64 threads = 1 wave
    int mbase = blockIdx.x * 16;       // 512 blocks
    floatx4 acc[6];
#pragma unroll
    for (int ni = 0; ni < 6; ++ni) acc[ni] = 0;
    int koff = (lane >> 4) * 8;
    int rlo  = lane & 15;
    const unsigned short* aptr = Aext_ro + (size_t)(mbase + rlo) * K_EXT + koff;
#pragma unroll 2
    for (int kt = 0; kt < 64; ++kt) {
        int k0 = kt * 32;
        short8 a = *(const short8*)(aptr + k0);
#pragma unroll
        for (int ni = 0; ni < 6; ++ni) {
            short8 b = *(const short8*)(AcatT + (size_t)(ni * 16 + rlo) * IN_DIM + k0 + koff);
            acc[ni] = __builtin_amdgcn_mfma_f32_16x16x32_bf16(a, b, acc[ni], 0, 0, 0);
        }
    }
#pragma unroll
    for (int ni = 0; ni < 6; ++ni) {
        int col = ni * 16 + rlo;
#pragma unroll
        for (int reg = 0; reg < 4; ++reg) {
            int row = mbase + (lane >> 4) * 4 + reg;
            float fac;
            if (col < 8)       fac = 1.f;
            else if (col < 72) fac = routing[(row >> 11) * NE + ((col - 8) >> 3)];
            else               fac = 0.f;
            Aext_w[(size_t)row * K_EXT + IN_DIM + col] = f2bf(acc[ni][reg] * fac);
        }
    }
}

// ------------- main GEMM: out[m][n] = A_ext[m][:] . B_ext[n][:] + bias[n], K=2144 -------------
#define BM 128
#define BN 128
#define BK 32
__global__ __launch_bounds__(256) void main_gemm(const unsigned short* __restrict__ A,
                                                 const unsigned short* __restrict__ B,
                                                 const float* __restrict__ bias,
                                                 float* __restrict__ out) {
    __shared__ unsigned short At[BM * BK];
    __shared__ unsigned short Bt[BN * BK];
    int t = threadIdx.x;
    int lane = t & 63;
    int w = t >> 6;
    int wm = w >> 1, wn = w & 1;
    int m0 = blockIdx.y * BM;
    int n0 = blockIdx.x * BN;

    floatx4 acc[4][4];
#pragma unroll
    for (int mi = 0; mi < 4; ++mi)
#pragma unroll
        for (int ni = 0; ni < 4; ++ni) acc[mi][ni] = 0;

    // staging: call q covers 64 rows; thread t -> row q*64 + t/4, col (t%4)*8
    int srow = t >> 2;
    int scol = (t & 3) * 8;
    const unsigned short* ga0 = A + (size_t)(m0 + srow) * K_EXT + scol;
    const unsigned short* ga1 = A + (size_t)(m0 + 64 + srow) * K_EXT + scol;
    const unsigned short* gb0 = B + (size_t)(n0 + srow) * K_EXT + scol;
    const unsigned short* gb1 = B + (size_t)(n0 + 64 + srow) * K_EXT + scol;
    unsigned short* lA0 = At + w * 512;
    unsigned short* lA1 = At + 2048 + w * 512;
    unsigned short* lB0 = Bt + w * 512;
    unsigned short* lB1 = Bt + 2048 + w * 512;

    int koff = (lane >> 4) * 8;
    int rlo  = lane & 15;

    for (int kt = 0; kt < K_EXT / BK; ++kt) {
        int k0 = kt * BK;
        gld_lds16(ga0 + k0, lA0);
        gld_lds16(ga1 + k0, lA1);
        gld_lds16(gb0 + k0, lB0);
        gld_lds16(gb1 + k0, lB1);
        __syncthreads();
        short8 af[4], bfr[4];
#pragma unroll
        for (int mi = 0; mi < 4; ++mi)
            af[mi] = *(const short8*)&At[(wm * 64 + mi * 16 + rlo) * BK + koff];
#pragma unroll
        for (int ni = 0; ni < 4; ++ni)
            bfr[ni] = *(const short8*)&Bt[(wn * 64 + ni * 16 + rlo) * BK + koff];
#pragma unroll
        for (int mi = 0; mi < 4; ++mi)
#pragma unroll
            for (int ni = 0; ni < 4; ++ni)
                acc[mi][ni] = __builtin_amdgcn_mfma_f32_16x16x32_bf16(af[mi], bfr[ni], acc[mi][ni], 0, 0, 0);
        __syncthreads();
    }

    float bb[4];
#pragma unroll
    for (int ni = 0; ni < 4; ++ni) bb[ni] = bias[n0 + wn * 64 + ni * 16 + rlo];
#pragma unroll
    for (int mi = 0; mi < 4; ++mi) {
        int row = m0 + wm * 64 + mi * 16 + (lane >> 4) * 4;
#pragma unroll
        for (int ni = 0; ni < 4; ++ni) {
            int col = n0 + wn * 64 + ni * 16 + rlo;
#pragma unroll
            for (int reg = 0; reg < 4; ++reg)
                out[(size_t)(row + reg) * OUT_DIM + col] = acc[mi][ni][reg] + bb[ni];
        }
    }
}

extern "C" void kernel_launch(void* const* d_in, const int* in_sizes, int n_in,
                              void* d_out, int out_size, void* d_ws, size_t ws_size,
                              hipStream_t stream) {
    const float* x   = (const float*)d_in[0];
    const float* rw  = (const float*)d_in[1];
    const float* W   = (const float*)d_in[2];
    const float* bv  = (const float*)d_in[3];
    const float* As  = (const float*)d_in[4];
    const float* Bs  = (const float*)d_in[5];
    const float* Ae  = (const float*)d_in[6];
    const float* Be  = (const float*)d_in[7];
    float* out = (float*)d_out;

    size_t offA = 0;
    size_t offB = offA + (size_t)M_TOT * K_EXT * sizeof(unsigned short);   // 35,127,296
    size_t offC = offB + (size_t)OUT_DIM * K_EXT * sizeof(unsigned short); // 43,909,120
    size_t need = offC + (size_t)RANK_PAD * IN_DIM * sizeof(unsigned short);
    if (ws_size < need) return;  // workspace too small; fail loudly via wrong output

    unsigned short* Aext  = (unsigned short*)((char*)d_ws + offA);
    unsigned short* Bext  = (unsigned short*)((char*)d_ws + offB);
    unsigned short* AcatT = (unsigned short*)((char*)d_ws + offC);

    prep_x<<<M_TOT, 256, 0, stream>>>(x, Aext);
    prep_w<<<OUT_DIM, 256, 0, stream>>>(W, Bs, Be, Bext);
    prep_acat<<<RANK_PAD, 256, 0, stream>>>(As, Ae, AcatT);
    tgemm<<<M_TOT / 16, 64, 0, stream>>>(Aext, Aext, AcatT, rw);
    main_gemm<<<dim3(OUT_DIM / BN, M_TOT / BM), 256, 0, stream>>>(Aext, Bext, bv, out);
}

// Round 2
// 124.709 us; speedup vs baseline: 1.8320x; 1.8320x over previous
//
#include <hip/hip_runtime.h>
#include <hip/hip_bf16.h>

#define IN_DIM 2048
#define OUT_DIM 2048
#define NE 8
#define M_TOT 8192          // B*S = 4*2048
#define RANK_PAD 128        // 8 shared + 64 expert + 24 zero + 32 align pad
#define K_EXT 2176          // IN_DIM + RANK_PAD, divisible by 64
#define NKT 34              // K_EXT / 64

typedef short short8 __attribute__((ext_vector_type(8)));
typedef float floatx4 __attribute__((ext_vector_type(4)));
typedef unsigned short us;

__device__ __forceinline__ us f2bf(float f) {
    union { float f; unsigned u; } v; v.f = f;
    unsigned r = v.u + 0x7FFFu + ((v.u >> 16) & 1u);   // round-to-nearest-even
    return (us)(r >> 16);
}

__device__ __forceinline__ void gld_lds16(const void* g, void* l) {
    __builtin_amdgcn_global_load_lds(
        (const __attribute__((address_space(1))) void*)g,
        (__attribute__((address_space(3))) void*)l, 16, 0, 0);
}

// ---------------------------------------------------------------------------
// 8-phase 256x256 main GEMM (m201 template, plain HIP).
// LDS: buffer b at b*65536; within buffer: A.K0 @0, B.K0 @16384, A.K1 @32768,
// B.K1 @49152 (each 16KB = 256 rows x 32 cols bf16, row = 64B = 4 x 16B slots).
// Swizzle: physical slot ps = logical slot s ^ (row & 3)  (involution).
// Staged via linear gld_lds dest + inverse-swizzled GLOBAL source (rule #21).
// Half-tile stream: S[4*tau+part], part: 0=A.K0 1=B.K0 2=A.K1 3=B.K1.
// Invariant: end of tile t -> tile t+1 fully landed, 3 halves (vmcnt 6) in flight.
// ---------------------------------------------------------------------------

__device__ __forceinline__ void stage_half(int h, const us* __restrict__ A,
                                           const us* __restrict__ B,
                                           int m0, int n0, int tid, char* smem) {
    int tau = h >> 2, part = h & 3;
    const us* g = (part & 1) ? (B + (size_t)n0 * K_EXT) : (A + (size_t)m0 * K_EXT);
    int kbase = tau * 64 + (part >> 1) * 32;
    char* lb = smem + (tau & 1) * 65536 + part * 16384 + (tid >> 6) * 1024;
#pragma unroll
    for (int j = 0; j < 2; ++j) {
        int q = j * 512 + tid;
        int r = q >> 2, ps = q & 3;
        const us* src = g + (size_t)r * K_EXT + kbase + ((ps ^ (r & 3)) * 8);
        gld_lds16(src, lb + j * 8192);
    }
}

__device__ __forceinline__ void mfma_quad(floatx4 (&acc)[8][4], const short8 (&af)[4],
                                          const short8 (&bf)[4], int mq) {
#pragma unroll
    for (int i = 0; i < 4; ++i)
#pragma unroll
        for (int ni = 0; ni < 4; ++ni)
            acc[mq * 4 + i][ni] =
                __builtin_amdgcn_mfma_f32_16x16x32_bf16(af[i], bf[ni], acc[mq * 4 + i][ni], 0, 0, 0);
}

template <int SMASK, int VMN>
__device__ __forceinline__ void ktile(int t, char* smem, const us* __restrict__ A,
                                      const us* __restrict__ B, int m0, int n0, int tid,
                                      int abyte0, int bbyte0, floatx4 (&acc)[8][4]) {
    const char* sm = smem + (t & 1) * 65536;
    const int sbase = 4 * t + 7;
    short8 af[4], bf[4];

    // ---- phase 1: kh0, mq0 (reads B kh0 + A[0..3] kh0) ----
#pragma unroll
    for (int ni = 0; ni < 4; ++ni) bf[ni] = *(const short8*)(sm + bbyte0 + ni * 1024);
#pragma unroll
    for (int i = 0; i < 4; ++i) af[i] = *(const short8*)(sm + abyte0 + i * 1024);
    if (SMASK & 1) stage_half(sbase + 0, A, B, m0, n0, tid, smem);
    __builtin_amdgcn_s_barrier();
    asm volatile("s_waitcnt lgkmcnt(0)" ::: "memory");
    __builtin_amdgcn_s_setprio(1);
    mfma_quad(acc, af, bf, 0);
    __builtin_amdgcn_s_setprio(0);
    __builtin_amdgcn_s_barrier();

    // ---- phase 2: kh0, mq1 (reads A[4..7] kh0; B held in regs) ----
#pragma unroll
    for (int i = 0; i < 4; ++i) af[i] = *(const short8*)(sm + abyte0 + (4 + i) * 1024);
    if (SMASK & 2) stage_half(sbase + 1, A, B, m0, n0, tid, smem);
    __builtin_amdgcn_s_barrier();
    asm volatile("s_waitcnt lgkmcnt(0)" ::: "memory");
    __builtin_amdgcn_s_setprio(1);
    mfma_quad(acc, af, bf, 1);
    __builtin_amdgcn_s_setprio(0);
    __builtin_amdgcn_s_barrier();

    // ---- phase 3: kh1, mq1 (reads B kh1 + A[4..7] kh1) ----
#pragma unroll
    for (int ni = 0; ni < 4; ++ni) bf[ni] = *(const short8*)(sm + 32768 + bbyte0 + ni * 1024);
#pragma unroll
    for (int i = 0; i < 4; ++i) af[i] = *(const short8*)(sm + 32768 + abyte0 + (4 + i) * 1024);
    if (SMASK & 4) stage_half(sbase + 2, A, B, m0, n0, tid, smem);
    __builtin_amdgcn_s_barrier();
    asm volatile("s_waitcnt lgkmcnt(0)" ::: "memory");
    __builtin_amdgcn_s_setprio(1);
    mfma_quad(acc, af, bf, 1);
    __builtin_amdgcn_s_setprio(0);
    __builtin_amdgcn_s_barrier();

    // ---- phase 4: kh1, mq0 (reads A[0..3] kh1) ----
#pragma unroll
    for (int i = 0; i < 4; ++i) af[i] = *(const short8*)(sm + 32768 + abyte0 + i * 1024);
    if (SMASK & 8) stage_half(sbase + 3, A, B, m0, n0, tid, smem);
    __builtin_amdgcn_s_barrier();
    asm volatile("s_waitcnt lgkmcnt(0)" ::: "memory");
    __builtin_amdgcn_s_setprio(1);
    mfma_quad(acc, af, bf, 0);
    __builtin_amdgcn_s_setprio(0);
    if (VMN == 6) asm volatile("s_waitcnt vmcnt(6)" ::: "memory");
    else if (VMN == 0) asm volatile("s_waitcnt vmcnt(0)" ::: "memory");
    __builtin_amdgcn_s_barrier();
}

__global__ __launch_bounds__(512) void main_gemm8(const us* __restrict__ A,
                                                  const us* __restrict__ B,
                                                  const float* __restrict__ bias,
                                                  float* __restrict__ out) {
    extern __shared__ char smem[];
    int tid = threadIdx.x;
    int lane = tid & 63, w = tid >> 6;
    int wm = w >> 2, wn = w & 3;          // 2M x 4N wave grid; per-wave C = 128x64
    int rlo = lane & 15, kq = lane >> 4;
    int m0 = blockIdx.y * 256, n0 = blockIdx.x * 256;
    int swz = (kq ^ (rlo & 3)) * 16;
    int abyte0 = (wm * 128 + rlo) * 64 + swz;            // + mi*1024 + kh*32768
    int bbyte0 = 16384 + (wn * 64 + rlo) * 64 + swz;     // + ni*1024 + kh*32768

    floatx4 acc[8][4];
#pragma unroll
    for (int mi = 0; mi < 8; ++mi)
#pragma unroll
        for (int ni = 0; ni < 4; ++ni) acc[mi][ni] = (floatx4)0.f;

    // prologue: stage S0..S6 (tile0 complete + 3 halves of tile1), land tile0
#pragma unroll
    for (int h = 0; h < 7; ++h) stage_half(h, A, B, m0, n0, tid, smem);
    asm volatile("s_waitcnt vmcnt(6)" ::: "memory");
    __builtin_amdgcn_s_barrier();

    for (int t = 0; t < 32; ++t)
        ktile<0xF, 6>(t, smem, A, B, m0, n0, tid, abyte0, bbyte0, acc);
    ktile<0x1, 0>(32, smem, A, B, m0, n0, tid, abyte0, bbyte0, acc);   // stage S135, drain
    ktile<0x0, -1>(33, smem, A, B, m0, n0, tid, abyte0, bbyte0, acc);  // compute only

    // epilogue: C[row,col] = acc + bias ; C/D map: col = rlo, row = kq*4 + reg
    float bb[4];
#pragma unroll
    for (int ni = 0; ni < 4; ++ni) bb[ni] = bias[n0 + wn * 64 + ni * 16 + rlo];
#pragma unroll
    for (int mi = 0; mi < 8; ++mi) {
        int row = m0 + wm * 128 + mi * 16 + kq * 4;
#pragma unroll
        for (int ni = 0; ni < 4; ++ni) {
            int col = n0 + wn * 64 + ni * 16 + rlo;
#pragma unroll
            for (int r = 0; r < 4; ++r)
                out[(size_t)(row + r) * OUT_DIM + col] = acc[mi][ni][r] + bb[ni];
        }
    }
}

// ---------------------------------------------------------------------------
// prep_w: W -> bf16 rows of B_ext; B_cat (B_s | B_e) into cols 2048+, zero pad
// ---------------------------------------------------------------------------
__global__ void prep_w(const float* __restrict__ W, const float* __restrict__ Bs,
                       const float* __restrict__ Be, us* __restrict__ Bext) {
    int n = blockIdx.x;
    int t = threadIdx.x;
    const float4* src = (const float4*)(W + (size_t)n * IN_DIM + t * 8);
    float4 v0 = src[0], v1 = src[1];
    short8 o;
    o[0] = (short)f2bf(v0.x); o[1] = (short)f2bf(v0.y); o[2] = (short)f2bf(v0.z); o[3] = (short)f2bf(v0.w);
    o[4] = (short)f2bf(v1.x); o[5] = (short)f2bf(v1.y); o[6] = (short)f2bf(v1.z); o[7] = (short)f2bf(v1.w);
    *(short8*)(Bext + (size_t)n * K_EXT + t * 8) = o;
    if (t < RANK_PAD) {
        float v = 0.f;
        if (t < 8)       v = Bs[(size_t)t * OUT_DIM + n];
        else if (t < 72) v = Be[(size_t)(t - 8) * OUT_DIM + n];
        Bext[(size_t)n * K_EXT + IN_DIM + t] = f2bf(v);
    }
}

// ---------------------------------------------------------------------------
// prep_acat: A_catT[96][2048] bf16; row k' = column k' of [A_s | A_e...]
// ---------------------------------------------------------------------------
__global__ void prep_acat(const float* __restrict__ As, const float* __restrict__ Ae,
                          us* __restrict__ AcatT) {
    int kp = blockIdx.x;          // 0..95
    int i0 = threadIdx.x * 8;
    short8 o;
#pragma unroll
    for (int j = 0; j < 8; ++j) {
        int i = i0 + j;
        float v = 0.f;
        if (kp < 8)       v = As[(size_t)i * 8 + kp];
        else if (kp < 72) v = Ae[(size_t)((kp - 8) >> 3) * IN_DIM * 8 + (size_t)i * 8 + ((kp - 8) & 7)];
        o[j] = (short)f2bf(v);
    }
    *(short8*)(AcatT + (size_t)kp * IN_DIM + i0) = o;
}

// ---------------------------------------------------------------------------
// tgemm_fused: reads x (f32), writes bf16 x into A_ext[:,0:2048], computes
// T = x@A_cat (rank 96) with K split across 4 waves + LDS reduce, writes
// routed/scaled T (bf16) into A_ext cols 2048..2143, zeros 2144..2175.
// ---------------------------------------------------------------------------
__global__ __launch_bounds__(256) void tgemm_fused(const float* __restrict__ x,
                                                   us* __restrict__ Aext,
                                                   const us* __restrict__ AcatT,
                                                   const float* __restrict__ routing) {
    __shared__ floatx4 red[4][64][6];
    int tid = threadIdx.x;
    int lane = tid & 63, w = tid >> 6;     // wave w owns K range [w*512, w*512+512)
    int rlo = lane & 15, kq = lane >> 4;
    int mbase = blockIdx.x * 16;

    floatx4 acc[6];
#pragma unroll
    for (int ni = 0; ni < 6; ++ni) acc[ni] = (floatx4)0.f;

    const float* xrow = x + (size_t)(mbase + rlo) * IN_DIM + w * 512 + kq * 8;
    us* arow = Aext + (size_t)(mbase + rlo) * K_EXT + w * 512 + kq * 8;
    const us* bbase = AcatT + (size_t)rlo * IN_DIM + w * 512 + kq * 8;

#pragma unroll 4
    for (int kt = 0; kt < 16; ++kt) {
        int k0 = kt * 32;
        float4 v0 = *(const float4*)(xrow + k0);
        float4 v1 = *(const float4*)(xrow + k0 + 4);
        short8 a;
        a[0] = (short)f2bf(v0.x); a[1] = (short)f2bf(v0.y); a[2] = (short)f2bf(v0.z); a[3] = (short)f2bf(v0.w);
        a[4] = (short)f2bf(v1.x); a[5] = (short)f2bf(v1.y); a[6] = (short)f2bf(v1.z); a[7] = (short)f2bf(v1.w);
        *(short8*)(arow + k0) = a;                     // bf16 x panel write
#pragma unroll
        for (int ni = 0; ni < 6; ++ni) {
            short8 b = *(const short8*)(bbase + (size_t)(ni * 16) * IN_DIM + k0);
            acc[ni] = __builtin_amdgcn_mfma_f32_16x16x32_bf16(a, b, acc[ni], 0, 0, 0);
        }
    }

#pragma unroll
    for (int ni = 0; ni < 6; ++ni) red[w][lane][ni] = acc[ni];
    __syncthreads();
    if (w == 0) {
#pragma unroll
        for (int ni = 0; ni < 6; ++ni) {
            floatx4 s = red[0][lane][ni];
#pragma unroll
            for (int ww = 1; ww < 4; ++ww) s += red[ww][lane][ni];
            int col = ni * 16 + rlo;
#pragma unroll
            for (int r = 0; r < 4; ++r) {
                int row = mbase + kq * 4 + r;
                float fac = (col < 8) ? 1.f
                          : (col < 72 ? routing[(row >> 11) * NE + ((col - 8) >> 3)] : 0.f);
                Aext[(size_t)row * K_EXT + IN_DIM + col] = f2bf(s[r] * fac);
            }
        }
#pragma unroll
        for (int c = 0; c < 2; ++c) {
            int col = 96 + c * 16 + rlo;
#pragma unroll
            for (int r = 0; r < 4; ++r)
                Aext[(size_t)(mbase + kq * 4 + r) * K_EXT + IN_DIM + col] = 0;
        }
    }
}

extern "C" void kernel_launch(void* const* d_in, const int* in_sizes, int n_in,
                              void* d_out, int out_size, void* d_ws, size_t ws_size,
                              hipStream_t stream) {
    const float* x   = (const float*)d_in[0];
    const float* rw  = (const float*)d_in[1];
    const float* W   = (const float*)d_in[2];
    const float* bv  = (const float*)d_in[3];
    const float* As  = (const float*)d_in[4];
    const float* Bs  = (const float*)d_in[5];
    const float* Ae  = (const float*)d_in[6];
    const float* Be  = (const float*)d_in[7];
    float* out = (float*)d_out;

    size_t offA = 0;
    size_t offB = offA + (size_t)M_TOT * K_EXT * sizeof(us);    // 35,651,584
    size_t offC = offB + (size_t)OUT_DIM * K_EXT * sizeof(us);  // +8,912,896
    size_t need = offC + (size_t)96 * IN_DIM * sizeof(us);      // +393,216
    if (ws_size < need) return;

    us* Aext  = (us*)((char*)d_ws + offA);
    us* Bext  = (us*)((char*)d_ws + offB);
    us* AcatT = (us*)((char*)d_ws + offC);

    hipFuncSetAttribute((const void*)main_gemm8,
                        hipFuncAttributeMaxDynamicSharedMemorySize, 131072);

    prep_acat<<<96, 256, 0, stream>>>(As, Ae, AcatT);
    prep_w<<<OUT_DIM, 256, 0, stream>>>(W, Bs, Be, Bext);
    tgemm_fused<<<M_TOT / 16, 256, 0, stream>>>(x, Aext, AcatT, rw);
    main_gemm8<<<dim3(OUT_DIM / 256, M_TOT / 256), 512, 131072, stream>>>(Aext, Bext, bv, out);
}

// Round 3
// 121.754 us; speedup vs baseline: 1.8764x; 1.0243x over previous
//
#include <hip/hip_runtime.h>
#include <hip/hip_bf16.h>

#define IN_DIM 2048
#define OUT_DIM 2048
#define NE 8
#define M_TOT 8192          // B*S = 4*2048
#define RANK_PAD 128        // 8 shared + 64 expert + 24 zero + 32 align pad
#define K_EXT 2176          // IN_DIM + RANK_PAD, divisible by 64
#define NKT 34              // K_EXT / 64

typedef short short8 __attribute__((ext_vector_type(8)));
typedef float floatx4 __attribute__((ext_vector_type(4)));
typedef unsigned short us;

__device__ __forceinline__ us f2bf(float f) {
    union { float f; unsigned u; } v; v.f = f;
    unsigned r = v.u + 0x7FFFu + ((v.u >> 16) & 1u);   // round-to-nearest-even
    return (us)(r >> 16);
}

__device__ __forceinline__ void gld_lds16(const void* g, void* l) {
    __builtin_amdgcn_global_load_lds(
        (const __attribute__((address_space(1))) void*)g,
        (__attribute__((address_space(3))) void*)l, 16, 0, 0);
}

// ---------------------------------------------------------------------------
// 8-phase 256x256 main GEMM (m201 template, plain HIP).
// LDS: buffer b at b*65536; within buffer: A.K0 @0, B.K0 @16384, A.K1 @32768,
// B.K1 @49152 (each 16KB = 256 rows x 32 cols bf16, row = 64B = 4 x 16B slots).
// Swizzle: physical slot ps = logical slot s ^ ((row>>1) & 3)  (involution).
//   Row stride is 64B=16 banks, so bank pattern repeats every 2 rows; XOR-ing
//   with (row>>1)&3 makes rows 0..7 cover all 8 (parity x slot) bank-quads ->
//   2-way max aliasing (free per m136). (row&3 left a 4-way conflict: rows
//   0,4,8,12 share parity AND slot.)
// Staged via linear gld_lds dest + inverse-swizzled GLOBAL source (rule #21).
// Half-tile stream: S[4*tau+part], part: 0=A.K0 1=B.K0 2=A.K1 3=B.K1.
// Invariant: end of tile t -> tile t+1 fully landed, 3 halves (vmcnt 6) in flight.
// ---------------------------------------------------------------------------

__device__ __forceinline__ void stage_half(int h, const us* __restrict__ A,
                                           const us* __restrict__ B,
                                           int m0, int n0, int tid, char* smem) {
    int tau = h >> 2, part = h & 3;
    const us* g = (part & 1) ? (B + (size_t)n0 * K_EXT) : (A + (size_t)m0 * K_EXT);
    int kbase = tau * 64 + (part >> 1) * 32;
    char* lb = smem + (tau & 1) * 65536 + part * 16384 + (tid >> 6) * 1024;
#pragma unroll
    for (int j = 0; j < 2; ++j) {
        int q = j * 512 + tid;
        int r = q >> 2, ps = q & 3;
        const us* src = g + (size_t)r * K_EXT + kbase + ((ps ^ ((r >> 1) & 3)) * 8);
        gld_lds16(src, lb + j * 8192);
    }
}

__device__ __forceinline__ void mfma_quad(floatx4 (&acc)[8][4], const short8 (&af)[4],
                                          const short8 (&bf)[4], int mq) {
#pragma unroll
    for (int i = 0; i < 4; ++i)
#pragma unroll
        for (int ni = 0; ni < 4; ++ni)
            acc[mq * 4 + i][ni] =
                __builtin_amdgcn_mfma_f32_16x16x32_bf16(af[i], bf[ni], acc[mq * 4 + i][ni], 0, 0, 0);
}

template <int SMASK, int VMN>
__device__ __forceinline__ void ktile(int t, char* smem, const us* __restrict__ A,
                                      const us* __restrict__ B, int m0, int n0, int tid,
                                      int abyte0, int bbyte0, floatx4 (&acc)[8][4]) {
    const char* sm = smem + (t & 1) * 65536;
    const int sbase = 4 * t + 7;
    short8 af[4], bf[4];

    // ---- phase 1: kh0, mq0 (reads B kh0 + A[0..3] kh0) ----
#pragma unroll
    for (int ni = 0; ni < 4; ++ni) bf[ni] = *(const short8*)(sm + bbyte0 + ni * 1024);
#pragma unroll
    for (int i = 0; i < 4; ++i) af[i] = *(const short8*)(sm + abyte0 + i * 1024);
    if (SMASK & 1) stage_half(sbase + 0, A, B, m0, n0, tid, smem);
    __builtin_amdgcn_s_barrier();
    asm volatile("s_waitcnt lgkmcnt(0)" ::: "memory");
    __builtin_amdgcn_s_setprio(1);
    mfma_quad(acc, af, bf, 0);
    __builtin_amdgcn_s_setprio(0);
    __builtin_amdgcn_s_barrier();

    // ---- phase 2: kh0, mq1 (reads A[4..7] kh0; B held in regs) ----
#pragma unroll
    for (int i = 0; i < 4; ++i) af[i] = *(const short8*)(sm + abyte0 + (4 + i) * 1024);
    if (SMASK & 2) stage_half(sbase + 1, A, B, m0, n0, tid, smem);
    __builtin_amdgcn_s_barrier();
    asm volatile("s_waitcnt lgkmcnt(0)" ::: "memory");
    __builtin_amdgcn_s_setprio(1);
    mfma_quad(acc, af, bf, 1);
    __builtin_amdgcn_s_setprio(0);
    __builtin_amdgcn_s_barrier();

    // ---- phase 3: kh1, mq1 (reads B kh1 + A[4..7] kh1) ----
#pragma unroll
    for (int ni = 0; ni < 4; ++ni) bf[ni] = *(const short8*)(sm + 32768 + bbyte0 + ni * 1024);
#pragma unroll
    for (int i = 0; i < 4; ++i) af[i] = *(const short8*)(sm + 32768 + abyte0 + (4 + i) * 1024);
    if (SMASK & 4) stage_half(sbase + 2, A, B, m0, n0, tid, smem);
    __builtin_amdgcn_s_barrier();
    asm volatile("s_waitcnt lgkmcnt(0)" ::: "memory");
    __builtin_amdgcn_s_setprio(1);
    mfma_quad(acc, af, bf, 1);
    __builtin_amdgcn_s_setprio(0);
    __builtin_amdgcn_s_barrier();

    // ---- phase 4: kh1, mq0 (reads A[0..3] kh1) ----
#pragma unroll
    for (int i = 0; i < 4; ++i) af[i] = *(const short8*)(sm + 32768 + abyte0 + i * 1024);
    if (SMASK & 8) stage_half(sbase + 3, A, B, m0, n0, tid, smem);
    __builtin_amdgcn_s_barrier();
    asm volatile("s_waitcnt lgkmcnt(0)" ::: "memory");
    __builtin_amdgcn_s_setprio(1);
    mfma_quad(acc, af, bf, 0);
    __builtin_amdgcn_s_setprio(0);
    if (VMN == 6) asm volatile("s_waitcnt vmcnt(6)" ::: "memory");
    else if (VMN == 0) asm volatile("s_waitcnt vmcnt(0)" ::: "memory");
    __builtin_amdgcn_s_barrier();
}

__global__ __launch_bounds__(512) void main_gemm8(const us* __restrict__ A,
                                                  const us* __restrict__ B,
                                                  const float* __restrict__ bias,
                                                  float* __restrict__ out) {
    extern __shared__ char smem[];
    int tid = threadIdx.x;
    int lane = tid & 63, w = tid >> 6;
    int wm = w >> 2, wn = w & 3;          // 2M x 4N wave grid; per-wave C = 128x64
    int rlo = lane & 15, kq = lane >> 4;
    int m0 = blockIdx.y * 256, n0 = blockIdx.x * 256;
    int swz = (kq ^ ((rlo >> 1) & 3)) * 16;
    int abyte0 = (wm * 128 + rlo) * 64 + swz;            // + mi*1024 + kh*32768
    int bbyte0 = 16384 + (wn * 64 + rlo) * 64 + swz;     // + ni*1024 + kh*32768

    floatx4 acc[8][4];
#pragma unroll
    for (int mi = 0; mi < 8; ++mi)
#pragma unroll
        for (int ni = 0; ni < 4; ++ni) acc[mi][ni] = (floatx4)0.f;

    // prologue: stage S0..S6 (tile0 complete + 3 halves of tile1), land tile0
#pragma unroll
    for (int h = 0; h < 7; ++h) stage_half(h, A, B, m0, n0, tid, smem);
    asm volatile("s_waitcnt vmcnt(6)" ::: "memory");
    __builtin_amdgcn_s_barrier();

    for (int t = 0; t < 32; ++t)
        ktile<0xF, 6>(t, smem, A, B, m0, n0, tid, abyte0, bbyte0, acc);
    ktile<0x1, 0>(32, smem, A, B, m0, n0, tid, abyte0, bbyte0, acc);   // stage S135, drain
    ktile<0x0, -1>(33, smem, A, B, m0, n0, tid, abyte0, bbyte0, acc);  // compute only

    // epilogue: C[row,col] = acc + bias ; C/D map: col = rlo, row = kq*4 + reg
    float bb[4];
#pragma unroll
    for (int ni = 0; ni < 4; ++ni) bb[ni] = bias[n0 + wn * 64 + ni * 16 + rlo];
#pragma unroll
    for (int mi = 0; mi < 8; ++mi) {
        int row = m0 + wm * 128 + mi * 16 + kq * 4;
#pragma unroll
        for (int ni = 0; ni < 4; ++ni) {
            int col = n0 + wn * 64 + ni * 16 + rlo;
#pragma unroll
            for (int r = 0; r < 4; ++r)
                out[(size_t)(row + r) * OUT_DIM + col] = acc[mi][ni][r] + bb[ni];
        }
    }
}

// ---------------------------------------------------------------------------
// prep_w: W -> bf16 rows of B_ext; B_cat (B_s | B_e) into cols 2048+, zero pad
// ---------------------------------------------------------------------------
__global__ void prep_w(const float* __restrict__ W, const float* __restrict__ Bs,
                       const float* __restrict__ Be, us* __restrict__ Bext) {
    int n = blockIdx.x;
    int t = threadIdx.x;
    const float4* src = (const float4*)(W + (size_t)n * IN_DIM + t * 8);
    float4 v0 = src[0], v1 = src[1];
    short8 o;
    o[0] = (short)f2bf(v0.x); o[1] = (short)f2bf(v0.y); o[2] = (short)f2bf(v0.z); o[3] = (short)f2bf(v0.w);
    o[4] = (short)f2bf(v1.x); o[5] = (short)f2bf(v1.y); o[6] = (short)f2bf(v1.z); o[7] = (short)f2bf(v1.w);
    *(short8*)(Bext + (size_t)n * K_EXT + t * 8) = o;
    if (t < RANK_PAD) {
        float v = 0.f;
        if (t < 8)       v = Bs[(size_t)t * OUT_DIM + n];
        else if (t < 72) v = Be[(size_t)(t - 8) * OUT_DIM + n];
        Bext[(size_t)n * K_EXT + IN_DIM + t] = f2bf(v);
    }
}

// ---------------------------------------------------------------------------
// prep_acat: A_catT[96][2048] bf16; row k' = column k' of [A_s | A_e...]
// ---------------------------------------------------------------------------
__global__ void prep_acat(const float* __restrict__ As, const float* __restrict__ Ae,
                          us* __restrict__ AcatT) {
    int kp = blockIdx.x;          // 0..95
    int i0 = threadIdx.x * 8;
    short8 o;
#pragma unroll
    for (int j = 0; j < 8; ++j) {
        int i = i0 + j;
        float v = 0.f;
        if (kp < 8)       v = As[(size_t)i * 8 + kp];
        else if (kp < 72) v = Ae[(size_t)((kp - 8) >> 3) * IN_DIM * 8 + (size_t)i * 8 + ((kp - 8) & 7)];
        o[j] = (short)f2bf(v);
    }
    *(short8*)(AcatT + (size_t)kp * IN_DIM + i0) = o;
}

// ---------------------------------------------------------------------------
// tgemm_fused: reads x (f32), writes bf16 x into A_ext[:,0:2048], computes
// T = x@A_cat (rank 96) with K split across 4 waves + LDS reduce, writes
// routed/scaled T (bf16) into A_ext cols 2048..2143, zeros 2144..2175.
// ---------------------------------------------------------------------------
__global__ __launch_bounds__(256) void tgemm_fused(const float* __restrict__ x,
                                                   us* __restrict__ Aext,
                                                   const us* __restrict__ AcatT,
                                                   const float* __restrict__ routing) {
    __shared__ floatx4 red[4][64][6];
    int tid = threadIdx.x;
    int lane = tid & 63, w = tid >> 6;     // wave w owns K range [w*512, w*512+512)
    int rlo = lane & 15, kq = lane >> 4;
    int mbase = blockIdx.x * 16;

    floatx4 acc[6];
#pragma unroll
    for (int ni = 0; ni < 6; ++ni) acc[ni] = (floatx4)0.f;

    const float* xrow = x + (size_t)(mbase + rlo) * IN_DIM + w * 512 + kq * 8;
    us* arow = Aext + (size_t)(mbase + rlo) * K_EXT + w * 512 + kq * 8;
    const us* bbase = AcatT + (size_t)rlo * IN_DIM + w * 512 + kq * 8;

#pragma unroll 4
    for (int kt = 0; kt < 16; ++kt) {
        int k0 = kt * 32;
        float4 v0 = *(const float4*)(xrow + k0);
        float4 v1 = *(const float4*)(xrow + k0 + 4);
        short8 a;
        a[0] = (short)f2bf(v0.x); a[1] = (short)f2bf(v0.y); a[2] = (short)f2bf(v0.z); a[3] = (short)f2bf(v0.w);
        a[4] = (short)f2bf(v1.x); a[5] = (short)f2bf(v1.y); a[6] = (short)f2bf(v1.z); a[7] = (short)f2bf(v1.w);
        *(short8*)(arow + k0) = a;                     // bf16 x panel write
#pragma unroll
        for (int ni = 0; ni < 6; ++ni) {
            short8 b = *(const short8*)(bbase + (size_t)(ni * 16) * IN_DIM + k0);
            acc[ni] = __builtin_amdgcn_mfma_f32_16x16x32_bf16(a, b, acc[ni], 0, 0, 0);
        }
    }

#pragma unroll
    for (int ni = 0; ni < 6; ++ni) red[w][lane][ni] = acc[ni];
    __syncthreads();
    if (w == 0) {
#pragma unroll
        for (int ni = 0; ni < 6; ++ni) {
            floatx4 s = red[0][lane][ni];
#pragma unroll
            for (int ww = 1; ww < 4; ++ww) s += red[ww][lane][ni];
            int col = ni * 16 + rlo;
#pragma unroll
            for (int r = 0; r < 4; ++r) {
                int row = mbase + kq * 4 + r;
                float fac = (col < 8) ? 1.f
                          : (col < 72 ? routing[(row >> 11) * NE + ((col - 8) >> 3)] : 0.f);
                Aext[(size_t)row * K_EXT + IN_DIM + col] = f2bf(s[r] * fac);
            }
        }
#pragma unroll
        for (int c = 0; c < 2; ++c) {
            int col = 96 + c * 16 + rlo;
#pragma unroll
            for (int r = 0; r < 4; ++r)
                Aext[(size_t)(mbase + kq * 4 + r) * K_EXT + IN_DIM + col] = 0;
        }
    }
}

extern "C" void kernel_launch(void* const* d_in, const int* in_sizes, int n_in,
                              void* d_out, int out_size, void* d_ws, size_t ws_size,
                              hipStream_t stream) {
    const float* x   = (const float*)d_in[0];
    const float* rw  = (const float*)d_in[1];
    const float* W   = (const float*)d_in[2];
    const float* bv  = (const float*)d_in[3];
    const float* As  = (const float*)d_in[4];
    const float* Bs  = (const float*)d_in[5];
    const float* Ae  = (const float*)d_in[6];
    const float* Be  = (const float*)d_in[7];
    float* out = (float*)d_out;

    size_t offA = 0;
    size_t offB = offA + (size_t)M_TOT * K_EXT * sizeof(us);    // 35,651,584
    size_t offC = offB + (size_t)OUT_DIM * K_EXT * sizeof(us);  // +8,912,896
    size_t need = offC + (size_t)96 * IN_DIM * sizeof(us);      // +393,216
    if (ws_size < need) return;

    us* Aext  = (us*)((char*)d_ws + offA);
    us* Bext  = (us*)((char*)d_ws + offB);
    us* AcatT = (us*)((char*)d_ws + offC);

    hipFuncSetAttribute((const void*)main_gemm8,
                        hipFuncAttributeMaxDynamicSharedMemorySize, 131072);

    prep_acat<<<96, 256, 0, stream>>>(As, Ae, AcatT);
    prep_w<<<OUT_DIM, 256, 0, stream>>>(W, Bs, Be, Bext);
    tgemm_fused<<<M_TOT / 16, 256, 0, stream>>>(x, Aext, AcatT, rw);
    main_gemm8<<<dim3(OUT_DIM / 256, M_TOT / 256), 512, 131072, stream>>>(Aext, Bext, bv, out);
}

// Round 4
// 117.383 us; speedup vs baseline: 1.9463x; 1.0372x over previous
//
#include <hip/hip_runtime.h>
#include <hip/hip_bf16.h>

#define IN_DIM 2048
#define OUT_DIM 2048
#define NE 8
#define M_TOT 8192          // B*S = 4*2048
#define RANK_PAD 128        // 8 shared + 64 expert + 24 zero + 32 align pad
#define K_EXT 2176          // IN_DIM + RANK_PAD, divisible by 64
#define NKT 34              // K_EXT / 64

typedef short short8 __attribute__((ext_vector_type(8)));
typedef float floatx4 __attribute__((ext_vector_type(4)));
typedef unsigned short us;

__device__ __forceinline__ us f2bf(float f) {
    union { float f; unsigned u; } v; v.f = f;
    unsigned r = v.u + 0x7FFFu + ((v.u >> 16) & 1u);   // round-to-nearest-even
    return (us)(r >> 16);
}

__device__ __forceinline__ void gld_lds16(const void* g, void* l) {
    __builtin_amdgcn_global_load_lds(
        (const __attribute__((address_space(1))) void*)g,
        (__attribute__((address_space(3))) void*)l, 16, 0, 0);
}

// ---------------------------------------------------------------------------
// 256x256 8-phase GEMM with READ-AHEAD register pipelining (R4).
// LDS buffer b at b*65536: A.K0 @0, B.K0 @16384, A.K1 @32768, B.K1 @49152.
// Swizzle (both sides, rule #21): slot ps = s ^ ((row>>1)&3).
//
// Per tile t, phases p0..p3. Fragment reads issued ONE PHASE AHEAD into
// double-buffered register sets (afA/afB, bfA/bfB) with counted lgkmcnt, so
// the LDS pipe drains UNDER the MFMA cluster instead of serial with it:
//   p0: rd A47kh0->afB  | lgkm(4) | MFMA mq0(afA,bfA) | stage A.K1(t+1) | vmcnt(8) BAR
//   p1: rd A47kh1->afA,
//       Bkh1  ->bfB     | lgkm(8) | MFMA mq1(afB,bfA) | stage B.K0(t+2) |          BAR
//   p2: rd A03kh1->afB  | lgkm(4) | MFMA mq1(afA,bfB) | stage A.K0(t+2) | vmcnt(8) BAR
//   p3: rd A03kh0,Bkh0
//       (next t)->afA,bfA| lgkm(8)| MFMA mq0(afB,bfB) | stage B.K1(t+2) |          BAR
// Hazard proof (cross-wave): stage(p) region is disjoint from read-sets
// issued in phases p-1 and p (the only possibly-in-flight reads, since each
// wave's lgkm in phase p-1 completed sets <= p-1 before BAR(p-1)).
// vmcnt(8): at end p0(t) issued halves = 7+4t+1; reads at p1 need A.K1(t)
// (half 4t+4 counting prologue 7) -> 4 halves = 8 loads outstanding allowed.
// Same math at p2 for next-tile A.K0/B.K0. Epilogue tiles: derived 8/4/0.
// ---------------------------------------------------------------------------

__device__ __forceinline__ void stage2(const us* src, char* lds) {
    gld_lds16(src, lds);
    gld_lds16(src + 128 * K_EXT, lds + 8192);
}

__device__ __forceinline__ void mfma_quad(floatx4 (&acc)[8][4], const short8 (&af)[4],
                                          const short8 (&bf)[4], int mq) {
#pragma unroll
    for (int i = 0; i < 4; ++i)
#pragma unroll
        for (int ni = 0; ni < 4; ++ni)
            acc[mq * 4 + i][ni] =
                __builtin_amdgcn_mfma_f32_16x16x32_bf16(af[i], bf[ni], acc[mq * 4 + i][ni], 0, 0, 0);
}

template <int SM, int VM0, int VM2, bool RD3>
__device__ __forceinline__ void ktile(
    const us* __restrict__ pA, const us* __restrict__ pB, int k1, int k2,
    const char* smC, const char* smN, char* lwC, char* lwN,
    int ab, int bb,
    short8 (&afA)[4], short8 (&afB)[4], short8 (&bfA)[4], short8 (&bfB)[4],
    floatx4 (&acc)[8][4])
{
    // ---------- p0 ----------
#pragma unroll
    for (int i = 0; i < 4; ++i) afB[i] = *(const short8*)(smC + ab + (4 + i) * 1024);
    asm volatile("s_waitcnt lgkmcnt(4)" ::: "memory");
    __builtin_amdgcn_sched_barrier(0);
    __builtin_amdgcn_s_setprio(1);
    mfma_quad(acc, afA, bfA, 0);
    __builtin_amdgcn_s_setprio(0);
    if (SM & 1) stage2(pA + k1 + 32, lwN + 32768);
    if (VM0 == 8)      asm volatile("s_waitcnt vmcnt(8)" ::: "memory");
    else if (VM0 == 0) asm volatile("s_waitcnt vmcnt(0)" ::: "memory");
    __builtin_amdgcn_s_barrier();

    // ---------- p1 ----------
#pragma unroll
    for (int i = 0; i < 4; ++i) afA[i] = *(const short8*)(smC + 32768 + ab + (4 + i) * 1024);
#pragma unroll
    for (int i = 0; i < 4; ++i) bfB[i] = *(const short8*)(smC + 32768 + bb + i * 1024);
    asm volatile("s_waitcnt lgkmcnt(8)" ::: "memory");
    __builtin_amdgcn_sched_barrier(0);
    __builtin_amdgcn_s_setprio(1);
    mfma_quad(acc, afB, bfA, 1);
    __builtin_amdgcn_s_setprio(0);
    if (SM & 2) stage2(pB + k2, lwC + 16384);
    __builtin_amdgcn_s_barrier();

    // ---------- p2 ----------
#pragma unroll
    for (int i = 0; i < 4; ++i) afB[i] = *(const short8*)(smC + 32768 + ab + i * 1024);
    asm volatile("s_waitcnt lgkmcnt(4)" ::: "memory");
    __builtin_amdgcn_sched_barrier(0);
    __builtin_amdgcn_s_setprio(1);
    mfma_quad(acc, afA, bfB, 1);
    __builtin_amdgcn_s_setprio(0);
    if (SM & 4) stage2(pA + k2, lwC);
    if (VM2 == 8)      asm volatile("s_waitcnt vmcnt(8)" ::: "memory");
    else if (VM2 == 4) asm volatile("s_waitcnt vmcnt(4)" ::: "memory");
    __builtin_amdgcn_s_barrier();

    // ---------- p3 ----------
    if (RD3) {
#pragma unroll
        for (int i = 0; i < 4; ++i) afA[i] = *(const short8*)(smN + ab + i * 1024);
#pragma unroll
        for (int i = 0; i < 4; ++i) bfA[i] = *(const short8*)(smN + bb + i * 1024);
        asm volatile("s_waitcnt lgkmcnt(8)" ::: "memory");
    } else {
        asm volatile("s_waitcnt lgkmcnt(0)" ::: "memory");
    }
    __builtin_amdgcn_sched_barrier(0);
    __builtin_amdgcn_s_setprio(1);
    mfma_quad(acc, afB, bfB, 0);
    __builtin_amdgcn_s_setprio(0);
    if (SM & 8) stage2(pB + k2 + 32, lwC + 49152);
    __builtin_amdgcn_s_barrier();
}

__global__ __launch_bounds__(512) void main_gemm8(const us* __restrict__ A,
                                                  const us* __restrict__ B,
                                                  const float* __restrict__ bias,
                                                  float* __restrict__ out) {
    extern __shared__ char smem[];
    int tid = threadIdx.x;
    int lane = tid & 63, w = tid >> 6;
    int wm = w >> 2, wn = w & 3;          // 2M x 4N waves; per-wave C = 128x64
    int rlo = lane & 15, kq = lane >> 4;

    // XCD-chunked swizzle: 256 blocks = 8 XCDs x 32; same-XCD blocks share A m-panels
    int b = blockIdx.x;
    int bs = (b & 7) * 32 + (b >> 3);
    int m0 = (bs >> 3) * 256, n0 = (bs & 7) * 256;

    int swz = (kq ^ ((rlo >> 1) & 3)) * 16;
    int ab = (wm * 128 + rlo) * 64 + swz;            // + mi*1024 + kh*32768
    int bb = 16384 + (wn * 64 + rlo) * 64 + swz;     // + ni*1024 + kh*32768

    // staging source pointers (pre-swizzled global, rule #21)
    int r0 = tid >> 2;
    int ps = tid & 3;
    int ssw = (ps ^ ((r0 >> 1) & 3)) * 8;
    const us* pA = A + (size_t)(m0 + r0) * K_EXT + ssw;
    const us* pB = B + (size_t)(n0 + r0) * K_EXT + ssw;
    char* lw0 = smem + w * 1024;
    char* lw1 = lw0 + 65536;
    const char* sm0 = smem;
    const char* sm1 = smem + 65536;

    floatx4 acc[8][4];
#pragma unroll
    for (int mi = 0; mi < 8; ++mi)
#pragma unroll
        for (int ni = 0; ni < 4; ++ni) acc[mi][ni] = (floatx4)0.f;

    // prologue: 7 halves (tile0 complete; tile1 A.K0,B.K0,B.K1)
    stage2(pA,      lw0);              // A.K0(0)
    stage2(pB,      lw0 + 16384);      // B.K0(0)
    stage2(pA + 32, lw0 + 32768);      // A.K1(0)
    stage2(pB + 32, lw0 + 49152);      // B.K1(0)
    stage2(pA + 64, lw1);              // A.K0(1)
    stage2(pB + 64, lw1 + 16384);      // B.K0(1)
    stage2(pB + 96, lw1 + 49152);      // B.K1(1)
    asm volatile("s_waitcnt vmcnt(10)" ::: "memory");   // first 2 halves landed
    __builtin_amdgcn_s_barrier();

    short8 afA[4], afB[4], bfA[4], bfB[4];
#pragma unroll
    for (int i = 0; i < 4; ++i) afA[i] = *(const short8*)(sm0 + ab + i * 1024);
#pragma unroll
    for (int i = 0; i < 4; ++i) bfA[i] = *(const short8*)(sm0 + bb + i * 1024);

    for (int tt = 0; tt < 16; ++tt) {
        int t0 = tt * 2;
        ktile<0xF, 8, 8, true>(pA, pB, (t0 + 1) * 64, (t0 + 2) * 64,
                               sm0, sm1, lw0, lw1, ab, bb, afA, afB, bfA, bfB, acc);
        ktile<0xF, 8, 8, true>(pA, pB, (t0 + 2) * 64, (t0 + 3) * 64,
                               sm1, sm0, lw1, lw0, ab, bb, afA, afB, bfA, bfB, acc);
    }
    // t=32: stage only A.K1(33); derived vmcnt 8 / 4
    ktile<0x1, 8, 4, true>(pA, pB, 33 * 64, 34 * 64,
                           sm0, sm1, lw0, lw1, ab, bb, afA, afB, bfA, bfB, acc);
    // t=33: compute only, drain
    ktile<0x0, 0, -1, false>(pA, pB, 0, 0,
                             sm1, sm0, lw1, lw0, ab, bb, afA, afB, bfA, bfB, acc);

    // epilogue: C/D map col=rlo, row=kq*4+reg
    float bbias[4];
#pragma unroll
    for (int ni = 0; ni < 4; ++ni) bbias[ni] = bias[n0 + wn * 64 + ni * 16 + rlo];
#pragma unroll
    for (int mi = 0; mi < 8; ++mi) {
        int row = m0 + wm * 128 + mi * 16 + kq * 4;
#pragma unroll
        for (int ni = 0; ni < 4; ++ni) {
            int col = n0 + wn * 64 + ni * 16 + rlo;
#pragma unroll
            for (int r = 0; r < 4; ++r)
                out[(size_t)(row + r) * OUT_DIM + col] = acc[mi][ni][r] + bbias[ni];
        }
    }
}

// ---------------------------------------------------------------------------
// prep_w: W -> bf16 rows of B_ext; B_cat (B_s | B_e) into cols 2048+, zero pad
// ---------------------------------------------------------------------------
__global__ void prep_w(const float* __restrict__ W, const float* __restrict__ Bs,
                       const float* __restrict__ Be, us* __restrict__ Bext) {
    int n = blockIdx.x;
    int t = threadIdx.x;
    const float4* src = (const float4*)(W + (size_t)n * IN_DIM + t * 8);
    float4 v0 = src[0], v1 = src[1];
    short8 o;
    o[0] = (short)f2bf(v0.x); o[1] = (short)f2bf(v0.y); o[2] = (short)f2bf(v0.z); o[3] = (short)f2bf(v0.w);
    o[4] = (short)f2bf(v1.x); o[5] = (short)f2bf(v1.y); o[6] = (short)f2bf(v1.z); o[7] = (short)f2bf(v1.w);
    *(short8*)(Bext + (size_t)n * K_EXT + t * 8) = o;
    if (t < RANK_PAD) {
        float v = 0.f;
        if (t < 8)       v = Bs[(size_t)t * OUT_DIM + n];
        else if (t < 72) v = Be[(size_t)(t - 8) * OUT_DIM + n];
        Bext[(size_t)n * K_EXT + IN_DIM + t] = f2bf(v);
    }
}

// ---------------------------------------------------------------------------
// prep_acat: A_catT[96][2048] bf16; row k' = column k' of [A_s | A_e...]
// ---------------------------------------------------------------------------
__global__ void prep_acat(const float* __restrict__ As, const float* __restrict__ Ae,
                          us* __restrict__ AcatT) {
    int kp = blockIdx.x;          // 0..95
    int i0 = threadIdx.x * 8;
    short8 o;
#pragma unroll
    for (int j = 0; j < 8; ++j) {
        int i = i0 + j;
        float v = 0.f;
        if (kp < 8)       v = As[(size_t)i * 8 + kp];
        else if (kp < 72) v = Ae[(size_t)((kp - 8) >> 3) * IN_DIM * 8 + (size_t)i * 8 + ((kp - 8) & 7)];
        o[j] = (short)f2bf(v);
    }
    *(short8*)(AcatT + (size_t)kp * IN_DIM + i0) = o;
}

// ---------------------------------------------------------------------------
// tgemm_fused: reads x (f32), writes bf16 x into A_ext[:,0:2048], computes
// T = x@A_cat (rank 96) K-split across 4 waves + LDS reduce, writes
// routed/scaled T (bf16) into A_ext cols 2048..2143, zeros 2144..2175.
// ---------------------------------------------------------------------------
__global__ __launch_bounds__(256) void tgemm_fused(const float* __restrict__ x,
                                                   us* __restrict__ Aext,
                                                   const us* __restrict__ AcatT,
                                                   const float* __restrict__ routing) {
    __shared__ floatx4 red[4][64][6];
    int tid = threadIdx.x;
    int lane = tid & 63, w = tid >> 6;
    int rlo = lane & 15, kq = lane >> 4;
    int mbase = blockIdx.x * 16;

    floatx4 acc[6];
#pragma unroll
    for (int ni = 0; ni < 6; ++ni) acc[ni] = (floatx4)0.f;

    const float* xrow = x + (size_t)(mbase + rlo) * IN_DIM + w * 512 + kq * 8;
    us* arow = Aext + (size_t)(mbase + rlo) * K_EXT + w * 512 + kq * 8;
    const us* bbase = AcatT + (size_t)rlo * IN_DIM + w * 512 + kq * 8;

#pragma unroll 4
    for (int kt = 0; kt < 16; ++kt) {
        int k0 = kt * 32;
        float4 v0 = *(const float4*)(xrow + k0);
        float4 v1 = *(const float4*)(xrow + k0 + 4);
        short8 a;
        a[0] = (short)f2bf(v0.x); a[1] = (short)f2bf(v0.y); a[2] = (short)f2bf(v0.z); a[3] = (short)f2bf(v0.w);
        a[4] = (short)f2bf(v1.x); a[5] = (short)f2bf(v1.y); a[6] = (short)f2bf(v1.z); a[7] = (short)f2bf(v1.w);
        *(short8*)(arow + k0) = a;
#pragma unroll
        for (int ni = 0; ni < 6; ++ni) {
            short8 bfr = *(const short8*)(bbase + (size_t)(ni * 16) * IN_DIM + k0);
            acc[ni] = __builtin_amdgcn_mfma_f32_16x16x32_bf16(a, bfr, acc[ni], 0, 0, 0);
        }
    }

#pragma unroll
    for (int ni = 0; ni < 6; ++ni) red[w][lane][ni] = acc[ni];
    __syncthreads();
    if (w == 0) {
#pragma unroll
        for (int ni = 0; ni < 6; ++ni) {
            floatx4 s = red[0][lane][ni];
#pragma unroll
            for (int ww = 1; ww < 4; ++ww) s += red[ww][lane][ni];
            int col = ni * 16 + rlo;
#pragma unroll
            for (int r = 0; r < 4; ++r) {
                int row = mbase + kq * 4 + r;
                float fac = (col < 8) ? 1.f
                          : (col < 72 ? routing[(row >> 11) * NE + ((col - 8) >> 3)] : 0.f);
                Aext[(size_t)row * K_EXT + IN_DIM + col] = f2bf(s[r] * fac);
            }
        }
#pragma unroll
        for (int c = 0; c < 2; ++c) {
            int col = 96 + c * 16 + rlo;
#pragma unroll
            for (int r = 0; r < 4; ++r)
                Aext[(size_t)(mbase + kq * 4 + r) * K_EXT + IN_DIM + col] = 0;
        }
    }
}

extern "C" void kernel_launch(void* const* d_in, const int* in_sizes, int n_in,
                              void* d_out, int out_size, void* d_ws, size_t ws_size,
                              hipStream_t stream) {
    const float* x   = (const float*)d_in[0];
    const float* rw  = (const float*)d_in[1];
    const float* W   = (const float*)d_in[2];
    const float* bv  = (const float*)d_in[3];
    const float* As  = (const float*)d_in[4];
    const float* Bs  = (const float*)d_in[5];
    const float* Ae  = (const float*)d_in[6];
    const float* Be  = (const float*)d_in[7];
    float* out = (float*)d_out;

    size_t offA = 0;
    size_t offB = offA + (size_t)M_TOT * K_EXT * sizeof(us);
    size_t offC = offB + (size_t)OUT_DIM * K_EXT * sizeof(us);
    size_t need = offC + (size_t)96 * IN_DIM * sizeof(us);
    if (ws_size < need) return;

    us* Aext  = (us*)((char*)d_ws + offA);
    us* Bext  = (us*)((char*)d_ws + offB);
    us* AcatT = (us*)((char*)d_ws + offC);

    hipFuncSetAttribute((const void*)main_gemm8,
                        hipFuncAttributeMaxDynamicSharedMemorySize, 131072);

    prep_acat<<<96, 256, 0, stream>>>(As, Ae, AcatT);
    prep_w<<<OUT_DIM, 256, 0, stream>>>(W, Bs, Be, Bext);
    tgemm_fused<<<M_TOT / 16, 256, 0, stream>>>(x, Aext, AcatT, rw);
    main_gemm8<<<256, 512, 131072, stream>>>(Aext, Bext, bv, out);
}